// Round 5
// baseline (340.306 us; speedup 1.0000x reference)
//
#include <hip/hip_runtime.h>

// Gaussian MMD distance as one weighted symmetric quadratic form over
// X = concat(a,b), weights +1/-1; upper-triangular 64x64 tiles only
// (off-diagonal x2). Per element: exp(-0.5*dm^2/vs) * rsqrt(vs).
// d processed in PAIRS via float2 arithmetic -> v_pk_{add,mul,fma}_f32;
// 2 transcendentals/element (v_rsq, v_exp) = the pipe floor (~29 us).
// This round: occupancy 8 waves/SIMD + register double-buffering of the
// LDS operand reads so the LDS pipe overlaps the trans pipe.

#define NTT 32                    // 64-row tiles per dim (2048/64)
#define NTRI (NTT*(NTT+1)/2)      // 528 upper-triangular tiles
#define DSPLIT 8                  // d split: each block does 16 d = 8 pairs
#define NPART (NTRI*DSPLIT)       // 4224 partials
#define PAIRS 8                   // d-pairs staged per block

#define MUSCALE 0.84932180028801904272f   // sqrt(0.5*log2(e))
#define LOG2E   1.4426950408889634f

__device__ __forceinline__ int tri_off(int b) {
  return b * (2 * NTT + 1 - b) / 2;
}

__global__ __launch_bounds__(256, 8) void pair_kernel(
    const float* __restrict__ mu_a, const float* __restrict__ lv_a,
    const float* __restrict__ mu_b, const float* __restrict__ lv_b,
    double* __restrict__ partials)
{
  // [side][row 64][pair 8]: float4 (mu0*C, mu1*C, var0, var1). 16 KiB.
  __shared__ float4 lds[2][64 * PAIRS];
  __shared__ double wsum[4];

  // ---- triangular tile decode: blockIdx.x in [0,528) -> (bi <= bj) ----
  const int k = blockIdx.x;
  int bi = (int)((2.0 * NTT + 1.0
                  - sqrt((2.0 * NTT + 1.0) * (2.0 * NTT + 1.0) - 8.0 * k)) * 0.5);
  if (bi < 0) bi = 0;
  if (bi > NTT - 1) bi = NTT - 1;
  while (tri_off(bi + 1) <= k) ++bi;
  while (tri_off(bi) > k) --bi;
  const int bj = bi + (k - tri_off(bi));

  const int rI = bi * 64, rJ = bj * 64;     // never straddle a/b boundary
  const float* muI = (rI < 1024) ? mu_a + rI * 128 : mu_b + (rI - 1024) * 128;
  const float* lvI = (rI < 1024) ? lv_a + rI * 128 : lv_b + (rI - 1024) * 128;
  const float* muJ = (rJ < 1024) ? mu_a + rJ * 128 : mu_b + (rJ - 1024) * 128;
  const float* lvJ = (rJ < 1024) ? lv_a + rJ * 128 : lv_b + (rJ - 1024) * 128;

  const int tid = threadIdx.x;
  const int dbase = blockIdx.y * (128 / DSPLIT);   // 16 d's per block

  // ---- stage: 1024 float4 slots, 4 per thread, coalesced float2 loads ----
  // swizzled slot: (row<<3) ^ (row&7) ^ p  (p < 8, low 3 bits free)
  #pragma unroll
  for (int it = 0; it < 4; ++it) {
    int s = tid + it * 256;            // [0, 1024)
    int side = s >> 9, rem = s & 511;
    int row = rem >> 3, p = rem & 7;
    const float2* m2 = (const float2*)((side == 0) ? muI : muJ);
    const float2* l2 = (const float2*)((side == 0) ? lvI : lvJ);
    int g = row * 64 + (dbase >> 1) + p;
    float2 m = m2[g], l = l2[g];
    lds[side][(row << 3) ^ (row & 7) ^ p] =
        make_float4(m.x * MUSCALE, m.y * MUSCALE,
                    __builtin_amdgcn_exp2f(l.x * LOG2E),
                    __builtin_amdgcn_exp2f(l.y * LOG2E));
  }
  __syncthreads();

  // ---- compute: 16x16 threads, 4x4 rows x 2 d's per ds_read_b128 ----
  const int tj = tid & 15, ti = tid >> 4;
  int baseI[4], baseJ[4];
  #pragma unroll
  for (int q = 0; q < 4; ++q) {
    baseI[q] = ((ti + 16 * q) << 3) ^ (ti & 7);   // (ti+16q)&7 == ti&7
    baseJ[q] = ((tj + 16 * q) << 3) ^ (tj & 7);
  }

  float2 acc[4][4];
  #pragma unroll
  for (int x = 0; x < 4; ++x)
    #pragma unroll
    for (int y = 0; y < 4; ++y) acc[x][y] = make_float2(0.f, 0.f);

  // register double-buffer: read pair p+1 while computing pair p
  float4 A[4], B[4], An[4], Bn[4];
  #pragma unroll
  for (int q = 0; q < 4; ++q) {
    A[q] = lds[0][baseI[q]];
    B[q] = lds[1][baseJ[q]];
  }

  #pragma unroll
  for (int p = 0; p < PAIRS; ++p) {
    if (p < PAIRS - 1) {
      #pragma unroll
      for (int q = 0; q < 4; ++q) {
        An[q] = lds[0][baseI[q] ^ (p + 1)];
        Bn[q] = lds[1][baseJ[q] ^ (p + 1)];
      }
    }
    #pragma unroll
    for (int x = 0; x < 4; ++x) {
      const float2 Amu = make_float2(A[x].x, A[x].y);
      const float2 Avr = make_float2(A[x].z, A[x].w);
      #pragma unroll
      for (int y = 0; y < 4; ++y) {
        const float2 Bmu = make_float2(B[y].x, B[y].y);
        const float2 Bvr = make_float2(B[y].z, B[y].w);
        float2 vs = Avr + Bvr;                       // v_pk_add_f32
        float2 r;
        r.x = __builtin_amdgcn_rsqf(vs.x);           // v_rsq_f32 [trans]
        r.y = __builtin_amdgcn_rsqf(vs.y);
        float2 dm = Amu - Bmu;                       // v_pk_add_f32 (neg)
        float2 t  = dm * r;                          // v_pk_mul_f32
        float2 m  = t * t;                           // v_pk_mul_f32
        float2 e;
        e.x = __builtin_amdgcn_exp2f(-m.x);          // v_exp_f32 [trans]
        e.y = __builtin_amdgcn_exp2f(-m.y);
        acc[x][y] += e * r;                          // v_pk_fma_f32
      }
    }
    #pragma unroll
    for (int q = 0; q < 4; ++q) { A[q] = An[q]; B[q] = Bn[q]; }
  }

  // ---- reduction: f32 pairwise -> f64 (cancellation safety) ----
  float2 s0 = make_float2(0.f, 0.f), s1 = make_float2(0.f, 0.f);
  #pragma unroll
  for (int x = 0; x < 4; ++x) {
    s0 += acc[x][0] + acc[x][1];
    s1 += acc[x][2] + acc[x][3];
  }
  double pdb = (double)(s0.x + s1.x) + (double)(s0.y + s1.y);
  for (int off = 32; off > 0; off >>= 1) pdb += __shfl_down(pdb, off, 64);

  if ((tid & 63) == 0) wsum[tid >> 6] = pdb;
  __syncthreads();
  if (tid == 0) {
    double t = (wsum[0] + wsum[1]) + (wsum[2] + wsum[3]);
    double w = ((bi < 16) == (bj < 16)) ? 1.0 : -1.0;   // sign s_I*s_J
    if (bi != bj) w *= 2.0;                              // symmetry factor
    partials[blockIdx.y * NTRI + blockIdx.x] = w * t;
  }
}

__global__ __launch_bounds__(1024) void final_reduce(
    const double* __restrict__ partials, float* __restrict__ out)
{
  __shared__ double wsum[16];
  double s = 0.0;
  for (int i = threadIdx.x; i < NPART; i += 1024) s += partials[i];
  for (int off = 32; off > 0; off >>= 1) s += __shfl_down(s, off, 64);
  if ((threadIdx.x & 63) == 0) wsum[threadIdx.x >> 6] = s;
  __syncthreads();
  if (threadIdx.x == 0) {
    double t = 0.0;
    #pragma unroll
    for (int wv = 0; wv < 16; ++wv) t += wsum[wv];
    out[0] = (float)(t * (1.0 / (1024.0 * 1024.0 * 128.0)));
  }
}

extern "C" void kernel_launch(void* const* d_in, const int* in_sizes, int n_in,
                              void* d_out, int out_size, void* d_ws, size_t ws_size,
                              hipStream_t stream) {
  const float* mu_a = (const float*)d_in[0];
  const float* lv_a = (const float*)d_in[1];
  const float* mu_b = (const float*)d_in[2];
  const float* lv_b = (const float*)d_in[3];
  float* out = (float*)d_out;
  double* partials = (double*)d_ws;   // NPART*8 = 33 KiB scratch

  dim3 grid(NTRI, DSPLIT);
  pair_kernel<<<grid, 256, 0, stream>>>(mu_a, lv_a, mu_b, lv_b, partials);
  final_reduce<<<1, 1024, 0, stream>>>(partials, out);
}

// Round 6
// 110.279 us; speedup vs baseline: 3.0859x; 3.0859x over previous
//
#include <hip/hip_runtime.h>

// Gaussian MMD distance as one weighted symmetric quadratic form over
// X = concat(a,b), weights +1/-1; upper-triangular 64x64 tiles only
// (off-diagonal x2). Per element: exp(-0.5*dm^2/vs) * rsqrt(vs).
// d processed in PAIRS via float2 arithmetic -> v_pk_{add,mul,fma}_f32;
// 2 transcendentals/element (v_rsq, v_exp) = the pipe floor (~28 us).
// R5: no explicit reg double-buffer (R4's spilled at the 8-wave VGPR cap);
// padded LDS layout (row stride 9 float4) so pair index p is a compile-time
// ds_read_b128 offset immediate -> zero per-read address VALU.

#define NTT 32                    // 64-row tiles per dim (2048/64)
#define NTRI (NTT*(NTT+1)/2)      // 528 upper-triangular tiles
#define DSPLIT 8                  // d split: each block does 16 d = 8 pairs
#define NPART (NTRI*DSPLIT)       // 4224 partials
#define PAIRS 8                   // d-pairs staged per block
#define RSTRIDE 9                 // float4 row stride (pad: 2-way banks, free)

#define MUSCALE 0.84932180028801904272f   // sqrt(0.5*log2(e))
#define LOG2E   1.4426950408889634f

__device__ __forceinline__ int tri_off(int b) {
  return b * (2 * NTT + 1 - b) / 2;
}

__global__ __launch_bounds__(256, 8) void pair_kernel(
    const float* __restrict__ mu_a, const float* __restrict__ lv_a,
    const float* __restrict__ mu_b, const float* __restrict__ lv_b,
    double* __restrict__ partials)
{
  // [side][row 64][pair 8 + pad]: float4 (mu0*C, mu1*C, var0, var1). 18 KiB.
  __shared__ float4 lds[2][64 * RSTRIDE];
  __shared__ double wsum[4];

  // ---- triangular tile decode: blockIdx.x in [0,528) -> (bi <= bj) ----
  const int k = blockIdx.x;
  int bi = (int)((2.0 * NTT + 1.0
                  - sqrt((2.0 * NTT + 1.0) * (2.0 * NTT + 1.0) - 8.0 * k)) * 0.5);
  if (bi < 0) bi = 0;
  if (bi > NTT - 1) bi = NTT - 1;
  while (tri_off(bi + 1) <= k) ++bi;
  while (tri_off(bi) > k) --bi;
  const int bj = bi + (k - tri_off(bi));

  const int rI = bi * 64, rJ = bj * 64;     // never straddle a/b boundary
  const float* muI = (rI < 1024) ? mu_a + rI * 128 : mu_b + (rI - 1024) * 128;
  const float* lvI = (rI < 1024) ? lv_a + rI * 128 : lv_b + (rI - 1024) * 128;
  const float* muJ = (rJ < 1024) ? mu_a + rJ * 128 : mu_b + (rJ - 1024) * 128;
  const float* lvJ = (rJ < 1024) ? lv_a + rJ * 128 : lv_b + (rJ - 1024) * 128;

  const int tid = threadIdx.x;
  const int dbase = blockIdx.y * (128 / DSPLIT);   // 16 d's per block

  // ---- stage: 1024 float4 slots, 4 per thread, coalesced float2 loads ----
  #pragma unroll
  for (int it = 0; it < 4; ++it) {
    int s = tid + it * 256;            // [0, 1024)
    int side = s >> 9, rem = s & 511;
    int row = rem >> 3, p = rem & 7;
    const float2* m2 = (const float2*)((side == 0) ? muI : muJ);
    const float2* l2 = (const float2*)((side == 0) ? lvI : lvJ);
    int g = row * 64 + (dbase >> 1) + p;
    float2 m = m2[g], l = l2[g];
    lds[side][row * RSTRIDE + p] =
        make_float4(m.x * MUSCALE, m.y * MUSCALE,
                    __builtin_amdgcn_exp2f(l.x * LOG2E),
                    __builtin_amdgcn_exp2f(l.y * LOG2E));
  }
  __syncthreads();

  // ---- compute: 16x16 threads, 4x4 rows x 2 d's per ds_read_b128 ----
  // A row addr depends only on ti (16 lanes broadcast); p is an offset imm.
  const int tj = tid & 15, ti = tid >> 4;
  const float4* baseA[4];
  const float4* baseB[4];
  #pragma unroll
  for (int q = 0; q < 4; ++q) {
    baseA[q] = &lds[0][(ti + 16 * q) * RSTRIDE];
    baseB[q] = &lds[1][(tj + 16 * q) * RSTRIDE];
  }

  float2 acc[4][4];
  #pragma unroll
  for (int x = 0; x < 4; ++x)
    #pragma unroll
    for (int y = 0; y < 4; ++y) acc[x][y] = make_float2(0.f, 0.f);

  #pragma unroll
  for (int p = 0; p < PAIRS; ++p) {
    float4 A[4], B[4];
    #pragma unroll
    for (int q = 0; q < 4; ++q) {
      A[q] = baseA[q][p];          // ds_read_b128 ..., offset:p*16
      B[q] = baseB[q][p];
    }
    #pragma unroll
    for (int x = 0; x < 4; ++x) {
      const float2 Amu = make_float2(A[x].x, A[x].y);
      const float2 Avr = make_float2(A[x].z, A[x].w);
      #pragma unroll
      for (int y = 0; y < 4; ++y) {
        const float2 Bmu = make_float2(B[y].x, B[y].y);
        const float2 Bvr = make_float2(B[y].z, B[y].w);
        float2 vs = Avr + Bvr;                       // v_pk_add_f32
        float2 r;
        r.x = __builtin_amdgcn_rsqf(vs.x);           // v_rsq_f32 [trans]
        r.y = __builtin_amdgcn_rsqf(vs.y);
        float2 dm = Amu - Bmu;                       // v_pk_add_f32 (neg)
        float2 t  = dm * r;                          // v_pk_mul_f32
        float2 m  = t * t;                           // v_pk_mul_f32
        float2 e;
        e.x = __builtin_amdgcn_exp2f(-m.x);          // v_exp_f32 [trans]
        e.y = __builtin_amdgcn_exp2f(-m.y);
        acc[x][y] += e * r;                          // v_pk_fma_f32
      }
    }
  }

  // ---- reduction: f32 pairwise -> f64 (cancellation safety) ----
  float2 s0 = make_float2(0.f, 0.f), s1 = make_float2(0.f, 0.f);
  #pragma unroll
  for (int x = 0; x < 4; ++x) {
    s0 += acc[x][0] + acc[x][1];
    s1 += acc[x][2] + acc[x][3];
  }
  double pdb = (double)(s0.x + s1.x) + (double)(s0.y + s1.y);
  for (int off = 32; off > 0; off >>= 1) pdb += __shfl_down(pdb, off, 64);

  if ((tid & 63) == 0) wsum[tid >> 6] = pdb;
  __syncthreads();
  if (tid == 0) {
    double t = (wsum[0] + wsum[1]) + (wsum[2] + wsum[3]);
    double w = ((bi < 16) == (bj < 16)) ? 1.0 : -1.0;   // sign s_I*s_J
    if (bi != bj) w *= 2.0;                              // symmetry factor
    partials[blockIdx.y * NTRI + blockIdx.x] = w * t;
  }
}

__global__ __launch_bounds__(1024) void final_reduce(
    const double* __restrict__ partials, float* __restrict__ out)
{
  __shared__ double wsum[16];
  double s = 0.0;
  for (int i = threadIdx.x; i < NPART; i += 1024) s += partials[i];
  for (int off = 32; off > 0; off >>= 1) s += __shfl_down(s, off, 64);
  if ((threadIdx.x & 63) == 0) wsum[threadIdx.x >> 6] = s;
  __syncthreads();
  if (threadIdx.x == 0) {
    double t = 0.0;
    #pragma unroll
    for (int wv = 0; wv < 16; ++wv) t += wsum[wv];
    out[0] = (float)(t * (1.0 / (1024.0 * 1024.0 * 128.0)));
  }
}

extern "C" void kernel_launch(void* const* d_in, const int* in_sizes, int n_in,
                              void* d_out, int out_size, void* d_ws, size_t ws_size,
                              hipStream_t stream) {
  const float* mu_a = (const float*)d_in[0];
  const float* lv_a = (const float*)d_in[1];
  const float* mu_b = (const float*)d_in[2];
  const float* lv_b = (const float*)d_in[3];
  float* out = (float*)d_out;
  double* partials = (double*)d_ws;   // NPART*8 = 33 KiB scratch

  dim3 grid(NTRI, DSPLIT);
  pair_kernel<<<grid, 256, 0, stream>>>(mu_a, lv_a, mu_b, lv_b, partials);
  final_reduce<<<1, 1024, 0, stream>>>(partials, out);
}

// Round 7
// 62.683 us; speedup vs baseline: 5.4290x; 1.7593x over previous
//
#include <hip/hip_runtime.h>

// Gaussian MMD distance as one weighted symmetric quadratic form over
// X = concat(a,b), weights +1/-1; upper-triangular 64x64 tiles only
// (off-diagonal x2). Per element: exp(-0.5*dm^2/vs) * rsqrt(vs).
// d processed in PAIRS via float2 arithmetic -> v_pk_{add,mul,fma}_f32;
// 2 transcendentals/element (v_rsq, v_exp) = the pipe floor (~28 us).
// R7 = R3's proven config (launch_bounds(256,6): VGPR cap 85, no spill)
// + padded RSTRIDE layout (pair index = ds_read_b128 offset immediate,
// no per-read XOR address math; pad keeps banks <=2-way = free).
// NOTE: launch_bounds(256,8) (VGPR cap 64) spills acc to scratch -> 5x
// regression (R4/R6, WRITE_SIZE 326MB). Do not lower the cap below ~80.

#define NTT 32                    // 64-row tiles per dim (2048/64)
#define NTRI (NTT*(NTT+1)/2)      // 528 upper-triangular tiles
#define DSPLIT 8                  // d split: each block does 16 d = 8 pairs
#define NPART (NTRI*DSPLIT)       // 4224 partials
#define PAIRS 8                   // d-pairs staged per block
#define RSTRIDE 9                 // float4 row stride (pad: <=2-way banks)

#define MUSCALE 0.84932180028801904272f   // sqrt(0.5*log2(e))
#define LOG2E   1.4426950408889634f

__device__ __forceinline__ int tri_off(int b) {
  return b * (2 * NTT + 1 - b) / 2;
}

__global__ __launch_bounds__(256, 6) void pair_kernel(
    const float* __restrict__ mu_a, const float* __restrict__ lv_a,
    const float* __restrict__ mu_b, const float* __restrict__ lv_b,
    double* __restrict__ partials)
{
  // [side][row 64][pair 8 + pad]: float4 (mu0*C, mu1*C, var0, var1). 18 KiB.
  __shared__ float4 lds[2][64 * RSTRIDE];
  __shared__ double wsum[4];

  // ---- triangular tile decode: blockIdx.x in [0,528) -> (bi <= bj) ----
  const int k = blockIdx.x;
  int bi = (int)((2.0 * NTT + 1.0
                  - sqrt((2.0 * NTT + 1.0) * (2.0 * NTT + 1.0) - 8.0 * k)) * 0.5);
  if (bi < 0) bi = 0;
  if (bi > NTT - 1) bi = NTT - 1;
  while (tri_off(bi + 1) <= k) ++bi;
  while (tri_off(bi) > k) --bi;
  const int bj = bi + (k - tri_off(bi));

  const int rI = bi * 64, rJ = bj * 64;     // never straddle a/b boundary
  const float* muI = (rI < 1024) ? mu_a + rI * 128 : mu_b + (rI - 1024) * 128;
  const float* lvI = (rI < 1024) ? lv_a + rI * 128 : lv_b + (rI - 1024) * 128;
  const float* muJ = (rJ < 1024) ? mu_a + rJ * 128 : mu_b + (rJ - 1024) * 128;
  const float* lvJ = (rJ < 1024) ? lv_a + rJ * 128 : lv_b + (rJ - 1024) * 128;

  const int tid = threadIdx.x;
  const int dbase = blockIdx.y * (128 / DSPLIT);   // 16 d's per block

  // ---- stage: 1024 float4 slots, 4 per thread, coalesced float2 loads ----
  #pragma unroll
  for (int it = 0; it < 4; ++it) {
    int s = tid + it * 256;            // [0, 1024)
    int side = s >> 9, rem = s & 511;
    int row = rem >> 3, p = rem & 7;
    const float2* m2 = (const float2*)((side == 0) ? muI : muJ);
    const float2* l2 = (const float2*)((side == 0) ? lvI : lvJ);
    int g = row * 64 + (dbase >> 1) + p;
    float2 m = m2[g], l = l2[g];
    lds[side][row * RSTRIDE + p] =
        make_float4(m.x * MUSCALE, m.y * MUSCALE,
                    __builtin_amdgcn_exp2f(l.x * LOG2E),
                    __builtin_amdgcn_exp2f(l.y * LOG2E));
  }
  __syncthreads();

  // ---- compute: 16x16 threads, 4x4 rows x 2 d's per ds_read_b128 ----
  // Row base addrs are loop-invariant; p is a compile-time offset immediate.
  const int tj = tid & 15, ti = tid >> 4;
  const float4* baseA[4];
  const float4* baseB[4];
  #pragma unroll
  for (int q = 0; q < 4; ++q) {
    baseA[q] = &lds[0][(ti + 16 * q) * RSTRIDE];
    baseB[q] = &lds[1][(tj + 16 * q) * RSTRIDE];
  }

  float2 acc[4][4];
  #pragma unroll
  for (int x = 0; x < 4; ++x)
    #pragma unroll
    for (int y = 0; y < 4; ++y) acc[x][y] = make_float2(0.f, 0.f);

  #pragma unroll
  for (int p = 0; p < PAIRS; ++p) {
    float4 A[4], B[4];
    #pragma unroll
    for (int q = 0; q < 4; ++q) {
      A[q] = baseA[q][p];          // ds_read_b128 ..., offset:p*16
      B[q] = baseB[q][p];
    }
    #pragma unroll
    for (int x = 0; x < 4; ++x) {
      const float2 Amu = make_float2(A[x].x, A[x].y);
      const float2 Avr = make_float2(A[x].z, A[x].w);
      #pragma unroll
      for (int y = 0; y < 4; ++y) {
        const float2 Bmu = make_float2(B[y].x, B[y].y);
        const float2 Bvr = make_float2(B[y].z, B[y].w);
        float2 vs = Avr + Bvr;                       // v_pk_add_f32
        float2 r;
        r.x = __builtin_amdgcn_rsqf(vs.x);           // v_rsq_f32 [trans]
        r.y = __builtin_amdgcn_rsqf(vs.y);
        float2 dm = Amu - Bmu;                       // v_pk_add_f32 (neg)
        float2 t  = dm * r;                          // v_pk_mul_f32
        float2 m  = t * t;                           // v_pk_mul_f32
        float2 e;
        e.x = __builtin_amdgcn_exp2f(-m.x);          // v_exp_f32 [trans]
        e.y = __builtin_amdgcn_exp2f(-m.y);
        acc[x][y] += e * r;                          // v_pk_fma_f32
      }
    }
  }

  // ---- reduction: f32 pairwise -> f64 (cancellation safety) ----
  float2 s0 = make_float2(0.f, 0.f), s1 = make_float2(0.f, 0.f);
  #pragma unroll
  for (int x = 0; x < 4; ++x) {
    s0 += acc[x][0] + acc[x][1];
    s1 += acc[x][2] + acc[x][3];
  }
  double pdb = (double)(s0.x + s1.x) + (double)(s0.y + s1.y);
  for (int off = 32; off > 0; off >>= 1) pdb += __shfl_down(pdb, off, 64);

  if ((tid & 63) == 0) wsum[tid >> 6] = pdb;
  __syncthreads();
  if (tid == 0) {
    double t = (wsum[0] + wsum[1]) + (wsum[2] + wsum[3]);
    double w = ((bi < 16) == (bj < 16)) ? 1.0 : -1.0;   // sign s_I*s_J
    if (bi != bj) w *= 2.0;                              // symmetry factor
    partials[blockIdx.y * NTRI + blockIdx.x] = w * t;
  }
}

__global__ __launch_bounds__(1024) void final_reduce(
    const double* __restrict__ partials, float* __restrict__ out)
{
  __shared__ double wsum[16];
  double s = 0.0;
  for (int i = threadIdx.x; i < NPART; i += 1024) s += partials[i];
  for (int off = 32; off > 0; off >>= 1) s += __shfl_down(s, off, 64);
  if ((threadIdx.x & 63) == 0) wsum[threadIdx.x >> 6] = s;
  __syncthreads();
  if (threadIdx.x == 0) {
    double t = 0.0;
    #pragma unroll
    for (int wv = 0; wv < 16; ++wv) t += wsum[wv];
    out[0] = (float)(t * (1.0 / (1024.0 * 1024.0 * 128.0)));
  }
}

extern "C" void kernel_launch(void* const* d_in, const int* in_sizes, int n_in,
                              void* d_out, int out_size, void* d_ws, size_t ws_size,
                              hipStream_t stream) {
  const float* mu_a = (const float*)d_in[0];
  const float* lv_a = (const float*)d_in[1];
  const float* mu_b = (const float*)d_in[2];
  const float* lv_b = (const float*)d_in[3];
  float* out = (float*)d_out;
  double* partials = (double*)d_ws;   // NPART*8 = 33 KiB scratch

  dim3 grid(NTRI, DSPLIT);
  pair_kernel<<<grid, 256, 0, stream>>>(mu_a, lv_a, mu_b, lv_b, partials);
  final_reduce<<<1, 1024, 0, stream>>>(partials, out);
}